// Round 1
// baseline (401.592 us; speedup 1.0000x reference)
//
#include <hip/hip_runtime.h>
#include <stdint.h>

#define THETA 16

// ---------------- workspace layout ----------------
// [0, 1572864)            : syn  u32[3][4096][32]  packed synapses: idx | (sign? 0xFF:0x01)<<24
// [1572864, 1622016)      : cnt  u32[3*4096]       per-row nonzero counters (atomic slots)
// [2097152, 2621440)      : bits_x  u64[16][4096]  transposed activation bits (bit = b&63)
// [2621440, 3145728)      : bits_a0
// [3145728, 3670016)      : bits_a1
// [3670016, 4194304)      : bits_a2
// needs ws_size >= 4 MiB

// Pack x[B=1024][F=4096] (floats in {0,1}) into transposed bitmasks bits[bg*4096 + f],
// bit (b&63) of the u64 = x[b][f] > 0.5.
__global__ __launch_bounds__(256) void pack_kernel(const float* __restrict__ x,
                                                   uint64_t* __restrict__ bits) {
    const int tid  = threadIdx.x;
    const int wave = tid >> 6;
    const int lane = tid & 63;
    const int bg   = blockIdx.y * 4 + wave;     // [0,16)
    const int f0   = blockIdx.x * 32;           // grid.x = 128
    const float* xr = x + (size_t)(bg * 64 + lane) * 4096;
    for (int fi = 0; fi < 32; ++fi) {
        const int f = f0 + fi;
        unsigned long long m = __ballot(xr[f] > 0.5f);
        if (lane == 0) bits[(size_t)bg * 4096 + f] = m;
    }
}

// Extract the sparse synapse list from the dense weights.
// Weight rows have exactly K=32 nonzeros, values +/-1.
__global__ __launch_bounds__(256) void sparsify_kernel(const float* __restrict__ w0,
                                                       const float* __restrict__ w1,
                                                       const float* __restrict__ w2,
                                                       uint32_t* __restrict__ syn,
                                                       uint32_t* __restrict__ cnt) {
    const int layer = blockIdx.y;
    const float* w = (layer == 0) ? w0 : ((layer == 1) ? w1 : w2);
    const size_t i = ((size_t)blockIdx.x * 256 + threadIdx.x) * 4;
    const float4 v = *(const float4*)(w + i);
    const int row   = (int)(i >> 12);      // 4096 cols per row
    const int col   = (int)(i & 4095);
    const int rbase = layer * 4096 + row;
    float vals[4] = {v.x, v.y, v.z, v.w};
#pragma unroll
    for (int k = 0; k < 4; ++k) {
        const float f = vals[k];
        if (f != 0.0f) {
            const uint32_t slot = atomicAdd(&cnt[rbase], 1u);
            if (slot < 32u) {
                syn[((size_t)rbase << 5) + slot] =
                    (uint32_t)(col + k) | (f < 0.0f ? 0xFF000000u : 0x01000000u);
            }
        }
    }
}

// One hidden layer: out bit (b) of neuron h = (sum_j sign_j * in_bit[idx_j][b]) >= THETA.
// Block: 256 thr (4 waves), fixed batch-group bg (64 batch rows), 64 neurons per block.
// Input bit-slice for this bg (4096 u64 = 32 KB) staged in LDS; synapse words are
// wave-uniform -> broadcast LDS reads, no bank conflicts.
__global__ __launch_bounds__(256) void layer_kernel(const uint64_t* __restrict__ in_bits,
                                                    const uint32_t* __restrict__ syn,
                                                    uint64_t* __restrict__ out_bits) {
    __shared__ uint32_t lb[8192];  // u64[4096] viewed as u32 pairs
    const int tid = threadIdx.x;
    const int bg  = blockIdx.y;

    const uint64_t* src = in_bits + (size_t)bg * 4096;
    uint64_t* d64 = (uint64_t*)lb;
#pragma unroll
    for (int i = 0; i < 16; ++i) d64[i * 256 + tid] = src[i * 256 + tid];
    __syncthreads();

    const int wave = tid >> 6;
    const int lane = tid & 63;
    const int l5   = lane & 31;
    const uint32_t hi = (uint32_t)(lane >> 5);
    const int h0 = blockIdx.x * 64 + wave * 16;

    for (int j = 0; j < 16; ++j) {
        const int hu = __builtin_amdgcn_readfirstlane(h0 + j);
        const uint32_t* sp = syn + ((size_t)hu << 5);
        int z = 0;
#pragma unroll
        for (int k = 0; k < 32; ++k) {
            const uint32_t sw  = sp[k];
            const int mult     = ((int)sw) >> 24;        // +1 / -1 / 0 (invalid slot)
            const uint32_t w32 = lb[((sw & 0xFFFFu) << 1) | hi];
            z += (int)((w32 >> l5) & 1u) * mult;
        }
        const unsigned long long m = __ballot(z >= THETA);
        if (lane == 0) out_bits[(size_t)bg * 4096 + hu] = m;
    }
}

// out[b][c] = sum_l sum_h act_l[b][h] * oc[l][h][c], act bits from the 3 layer buffers.
__global__ __launch_bounds__(64) void out_kernel(const uint64_t* __restrict__ bits0,
                                                 const float* __restrict__ oc,
                                                 float* __restrict__ out) {
    const int b    = blockIdx.x;
    const int lane = threadIdx.x;
    const int bg   = b >> 6;
    const int sh   = b & 63;
    float acc[10];
#pragma unroll
    for (int c = 0; c < 10; ++c) acc[c] = 0.0f;

    for (int l = 0; l < 3; ++l) {
        const uint64_t* base = bits0 + (size_t)l * 65536 + (size_t)bg * 4096;
        for (int h = lane; h < 4096; h += 64) {
            const uint64_t w = base[h];
            if ((w >> sh) & 1ull) {
                const float* o = oc + (size_t)(l * 4096 + h) * 10;
#pragma unroll
                for (int c = 0; c < 10; ++c) acc[c] += o[c];
            }
        }
    }
#pragma unroll
    for (int c = 0; c < 10; ++c) {
#pragma unroll
        for (int off = 32; off > 0; off >>= 1) acc[c] += __shfl_down(acc[c], off);
    }
    if (lane == 0) {
#pragma unroll
        for (int c = 0; c < 10; ++c) out[b * 10 + c] = acc[c];
    }
}

extern "C" void kernel_launch(void* const* d_in, const int* in_sizes, int n_in,
                              void* d_out, int out_size, void* d_ws, size_t ws_size,
                              hipStream_t stream) {
    const float* x  = (const float*)d_in[0];
    const float* w0 = (const float*)d_in[1];
    const float* w1 = (const float*)d_in[2];
    const float* w2 = (const float*)d_in[3];
    const float* oc = (const float*)d_in[4];
    float* out = (float*)d_out;

    uint32_t* syn   = (uint32_t*)d_ws;
    uint64_t* bitsx = (uint64_t*)((char*)d_ws + 2097152);
    uint64_t* bits0 = bitsx + 65536;
    uint64_t* bits1 = bits0 + 65536;
    uint64_t* bits2 = bits1 + 65536;

    // zero synapse slots + atomic counters (harness poisons ws with 0xAA)
    hipMemsetAsync(d_ws, 0, 1622016, stream);

    pack_kernel<<<dim3(128, 4), 256, 0, stream>>>(x, bitsx);
    sparsify_kernel<<<dim3(16384, 3), 256, 0, stream>>>(w0, w1, w2, syn, (uint32_t*)((char*)d_ws + 1572864));

    layer_kernel<<<dim3(64, 16), 256, 0, stream>>>(bitsx, syn,                bits0);
    layer_kernel<<<dim3(64, 16), 256, 0, stream>>>(bits0, syn + 4096 * 32,    bits1);
    layer_kernel<<<dim3(64, 16), 256, 0, stream>>>(bits1, syn + 2 * 4096 * 32, bits2);

    out_kernel<<<1024, 64, 0, stream>>>(bits0, oc, out);
}

// Round 2
// 236.976 us; speedup vs baseline: 1.6947x; 1.6947x over previous
//
#include <hip/hip_runtime.h>
#include <stdint.h>

// ---------------- workspace layout ----------------
// [0, 1572864)        : syn  u32[3][4096][32]  packed synapses: col(12b) | sign<<31
// [2097152, 2621440)  : bits_x  u64[16][4096]  transposed activation bits (bit = b&63)
// [2621440, 3145728)  : bits_a0
// [3145728, 3670016)  : bits_a1
// [3670016, 4194304)  : bits_a2

// Pack x[1024][4096] -> transposed bitmasks. Thread owns one column, streams 64 rows
// (coalesced 1KB per wave-load), accumulates bits in a register.
__global__ __launch_bounds__(256) void pack_kernel(const float* __restrict__ x,
                                                   uint64_t* __restrict__ bits) {
    const int c  = blockIdx.x * 256 + threadIdx.x;  // 0..4095
    const int bg = blockIdx.y;                      // 0..15
    const float* xp = x + (size_t)bg * 64 * 4096 + c;
    uint64_t acc = 0;
#pragma unroll
    for (int r = 0; r < 64; ++r) {
        const float v = xp[(size_t)r * 4096];
        acc |= (uint64_t)(v > 0.5f) << r;
    }
    bits[(size_t)bg * 4096 + c] = acc;
}

// Atomic-free sparsify: one wave per weight row. Slot order within a row is
// irrelevant (the dot product is a sum), so slots are assigned by ballot-prefix.
__global__ __launch_bounds__(256) void sparsify_kernel(const float* __restrict__ w0,
                                                       const float* __restrict__ w1,
                                                       const float* __restrict__ w2,
                                                       uint32_t* __restrict__ syn) {
    const int wid   = blockIdx.x * 4 + (threadIdx.x >> 6);  // row 0..12287
    const int lane  = threadIdx.x & 63;
    const int layer = wid >> 12;
    const int r     = wid & 4095;
    const float* wp = (layer == 0 ? w0 : (layer == 1 ? w1 : w2)) + (size_t)r * 4096;
    uint32_t* srow  = syn + (size_t)wid * 32;
    const uint64_t lt = (1ull << lane) - 1ull;
    uint32_t base = 0;
    for (int it = 0; it < 16; ++it) {
        const int col = it * 256 + lane * 4;
        const float4 v = *(const float4*)(wp + col);
        const uint64_t m0 = __ballot(v.x != 0.0f);
        const uint64_t m1 = __ballot(v.y != 0.0f);
        const uint64_t m2 = __ballot(v.z != 0.0f);
        const uint64_t m3 = __ballot(v.w != 0.0f);
        const uint32_t t0 = (uint32_t)__popcll(m0), t1 = (uint32_t)__popcll(m1);
        const uint32_t t2 = (uint32_t)__popcll(m2), t3 = (uint32_t)__popcll(m3);
        if (v.x != 0.0f) { const uint32_t s = base + (uint32_t)__popcll(m0 & lt);
            if (s < 32u) srow[s] = (uint32_t)col | (v.x < 0.0f ? 0x80000000u : 0u); }
        if (v.y != 0.0f) { const uint32_t s = base + t0 + (uint32_t)__popcll(m1 & lt);
            if (s < 32u) srow[s] = (uint32_t)(col + 1) | (v.y < 0.0f ? 0x80000000u : 0u); }
        if (v.z != 0.0f) { const uint32_t s = base + t0 + t1 + (uint32_t)__popcll(m2 & lt);
            if (s < 32u) srow[s] = (uint32_t)(col + 2) | (v.z < 0.0f ? 0x80000000u : 0u); }
        if (v.w != 0.0f) { const uint32_t s = base + t0 + t1 + t2 + (uint32_t)__popcll(m3 & lt);
            if (s < 32u) srow[s] = (uint32_t)(col + 3) | (v.w < 0.0f ? 0x80000000u : 0u); }
        base += t0 + t1 + t2 + t3;
    }
}

// Bit-sliced layer: each thread computes all 64 batch-bits of ONE neuron using
// carry-save bitplane counters over u64 input-bit masks.
// z = P - N >= 16  <=>  sum_k t_k >= 16 + Nneg, where t_k = b (pos) / ~b (neg).
__global__ __launch_bounds__(256) void layer_kernel(const uint64_t* __restrict__ in_bits,
                                                    const uint32_t* __restrict__ syn,
                                                    uint64_t* __restrict__ out_bits) {
    __shared__ uint64_t lb[4096];  // this bg's input bit-slice, 32 KB
    const int tid = threadIdx.x;
    const int bg  = blockIdx.y;
    const uint64_t* src = in_bits + (size_t)bg * 4096;
#pragma unroll
    for (int i = 0; i < 8; ++i)
        ((uint4*)lb)[i * 256 + tid] = ((const uint4*)src)[i * 256 + tid];
    __syncthreads();

    const int h = blockIdx.x * 256 + tid;
    const uint32_t* srow = syn + (size_t)h * 32;
    uint32_t sw[32];
#pragma unroll
    for (int k = 0; k < 8; ++k)
        *(uint4*)(sw + k * 4) = *(const uint4*)(srow + k * 4);

    uint32_t thr = 16;
#pragma unroll
    for (int k = 0; k < 32; ++k) thr += sw[k] >> 31;

    // two independent 5-plane counters (16 synapses each) for ILP
    uint64_t a0 = 0, a1 = 0, a2 = 0, a3 = 0, a4 = 0;
    uint64_t b0 = 0, b1 = 0, b2 = 0, b3 = 0, b4 = 0;
#pragma unroll
    for (int k = 0; k < 32; k += 2) {
        {
            const uint32_t s = sw[k];
            uint64_t c = lb[s & 4095] ^ (uint64_t)(int64_t)((int32_t)s >> 31);
            uint64_t t;
            t = a0 & c; a0 ^= c; c = t;
            t = a1 & c; a1 ^= c; c = t;
            t = a2 & c; a2 ^= c; c = t;
            t = a3 & c; a3 ^= c; c = t;
            a4 ^= c;
        }
        {
            const uint32_t s = sw[k + 1];
            uint64_t c = lb[s & 4095] ^ (uint64_t)(int64_t)((int32_t)s >> 31);
            uint64_t t;
            t = b0 & c; b0 ^= c; c = t;
            t = b1 & c; b1 ^= c; c = t;
            t = b2 & c; b2 ^= c; c = t;
            t = b3 & c; b3 ^= c; c = t;
            b4 ^= c;
        }
    }
    // merge: v = A + B (bitwise ripple-carry across planes)
    uint64_t c;
    const uint64_t v0 = a0 ^ b0;     c = a0 & b0;
    const uint64_t v1 = a1 ^ b1 ^ c; c = (a1 & b1) | (c & (a1 ^ b1));
    const uint64_t v2 = a2 ^ b2 ^ c; c = (a2 & b2) | (c & (a2 ^ b2));
    const uint64_t v3 = a3 ^ b3 ^ c; c = (a3 & b3) | (c & (a3 ^ b3));
    const uint64_t v4 = a4 ^ b4 ^ c; c = (a4 & b4) | (c & (a4 ^ b4));
    const uint64_t v5 = c;
    // bitwise (v >= thr) over the 64 bit-positions, MSB-first compare
    uint64_t gt = 0, eq = ~0ull;
    {
        uint64_t tb;
        tb = ((thr >> 5) & 1u) ? ~0ull : 0ull; gt |= eq & v5 & ~tb; eq &= ~(v5 ^ tb);
        tb = ((thr >> 4) & 1u) ? ~0ull : 0ull; gt |= eq & v4 & ~tb; eq &= ~(v4 ^ tb);
        tb = ((thr >> 3) & 1u) ? ~0ull : 0ull; gt |= eq & v3 & ~tb; eq &= ~(v3 ^ tb);
        tb = ((thr >> 2) & 1u) ? ~0ull : 0ull; gt |= eq & v2 & ~tb; eq &= ~(v2 ^ tb);
        tb = ((thr >> 1) & 1u) ? ~0ull : 0ull; gt |= eq & v1 & ~tb; eq &= ~(v1 ^ tb);
        tb = ((thr >> 0) & 1u) ? ~0ull : 0ull; gt |= eq & v0 & ~tb; eq &= ~(v0 ^ tb);
    }
    out_bits[(size_t)bg * 4096 + h] = gt | eq;
}

// out[b][c] = sum_l sum_h act * oc. One block (4 waves) per batch row b.
__global__ __launch_bounds__(256) void out_kernel(const uint64_t* __restrict__ bits,
                                                  const float* __restrict__ oc,
                                                  float* __restrict__ out) {
    __shared__ float red[4][10];
    const int b   = blockIdx.x;
    const int tid = threadIdx.x;
    const int bg  = b >> 6;
    const int sh  = b & 63;
    float acc[10];
#pragma unroll
    for (int cc = 0; cc < 10; ++cc) acc[cc] = 0.0f;
#pragma unroll
    for (int l = 0; l < 3; ++l) {
        const uint64_t* base = bits + (size_t)l * 65536 + (size_t)bg * 4096;
        const float* ocl = oc + (size_t)l * 40960;
#pragma unroll
        for (int i = 0; i < 16; ++i) {
            const int h = i * 256 + tid;
            const uint64_t w = base[h];
            if ((w >> sh) & 1ull) {
                const float* o = ocl + (size_t)h * 10;
#pragma unroll
                for (int cc = 0; cc < 10; ++cc) acc[cc] += o[cc];
            }
        }
    }
#pragma unroll
    for (int cc = 0; cc < 10; ++cc) {
#pragma unroll
        for (int off = 32; off > 0; off >>= 1) acc[cc] += __shfl_down(acc[cc], off);
    }
    const int wave = tid >> 6;
    if ((tid & 63) == 0) {
#pragma unroll
        for (int cc = 0; cc < 10; ++cc) red[wave][cc] = acc[cc];
    }
    __syncthreads();
    if (tid < 10)
        out[(size_t)b * 10 + tid] = red[0][tid] + red[1][tid] + red[2][tid] + red[3][tid];
}

extern "C" void kernel_launch(void* const* d_in, const int* in_sizes, int n_in,
                              void* d_out, int out_size, void* d_ws, size_t ws_size,
                              hipStream_t stream) {
    const float* x  = (const float*)d_in[0];
    const float* w0 = (const float*)d_in[1];
    const float* w1 = (const float*)d_in[2];
    const float* w2 = (const float*)d_in[3];
    const float* oc = (const float*)d_in[4];
    float* out = (float*)d_out;

    uint32_t* syn   = (uint32_t*)d_ws;
    uint64_t* bitsx = (uint64_t*)((char*)d_ws + 2097152);
    uint64_t* bits0 = bitsx + 65536;
    uint64_t* bits1 = bits0 + 65536;
    uint64_t* bits2 = bits1 + 65536;

    pack_kernel<<<dim3(16, 16), 256, 0, stream>>>(x, bitsx);
    sparsify_kernel<<<3072, 256, 0, stream>>>(w0, w1, w2, syn);

    layer_kernel<<<dim3(16, 16), 256, 0, stream>>>(bitsx, syn,          bits0);
    layer_kernel<<<dim3(16, 16), 256, 0, stream>>>(bits0, syn + 131072, bits1);
    layer_kernel<<<dim3(16, 16), 256, 0, stream>>>(bits1, syn + 262144, bits2);

    out_kernel<<<1024, 256, 0, stream>>>(bits0, oc, out);
}